// Round 13
// baseline (3344.307 us; speedup 1.0000x reference)
//
#include <hip/hip_runtime.h>

#define T_STEPS 200
#define BATCH   32
#define HID     1024
#define NTHR    512
#define HB      (BATCH * HID)

typedef _Float16 half8 __attribute__((ext_vector_type(8)));
typedef float    f32x4 __attribute__((ext_vector_type(4)));
typedef unsigned long long u64;

#define RLX __ATOMIC_RELAXED
#define AGT __HIP_MEMORY_SCOPE_AGENT

// uncached (agent-scope, LLC write-through) 16B store for producer h/y publishes
__device__ __forceinline__ void st_coh16(_Float16* p, half8 v) {
    union { half8 h; u64 u[2]; } r; r.h = v;
    u64* q = (u64*)p;
    __hip_atomic_store(q,     r.u[0], RLX, AGT);
    __hip_atomic_store(q + 1, r.u[1], RLX, AGT);
}
static __device__ __forceinline__ unsigned lda32(const unsigned* p){
    return __hip_atomic_load(p, RLX, AGT); }
static __device__ __forceinline__ void sta32(unsigned* p, unsigned v){
    __hip_atomic_store(p, v, RLX, AGT); }

__device__ __forceinline__ half8 cvt8(const float* p) {
    f32x4 lo = *(const f32x4*)p;
    f32x4 hi = *(const f32x4*)(p + 4);
    half8 a;
    a[0]=(_Float16)lo[0]; a[1]=(_Float16)lo[1]; a[2]=(_Float16)lo[2]; a[3]=(_Float16)lo[3];
    a[4]=(_Float16)hi[0]; a[5]=(_Float16)hi[1]; a[6]=(_Float16)hi[2]; a[7]=(_Float16)hi[3];
    return a;
}

__global__ void init_k(const float* __restrict__ h0,
                       _Float16* __restrict__ h0b, _Float16* __restrict__ h1b,
                       unsigned* __restrict__ flag0, unsigned* __restrict__ flag1) {
    int i = blockIdx.x * blockDim.x + threadIdx.x;
    if (i < HB) {
        h0b[i] = (_Float16)h0[i];                 // layer 0 initial h -> slot 0
        h1b[i] = (_Float16)h0[HB + i];            // layer 1 initial h -> slot 0
    }
    if (i < 8192) { flag0[i] = 0u; flag1[i] = 0u; }   // 2 groups x 128 flags x 32-word stride
}

// R7 champion chassis + G=2 batch-group pipelining. 256 WGs x 512 thr:
// WGs 0-127 layer 0, 128-255 layer 1; weights persist in LDS (XOR-swizzle).
// The 32 batch rows split into 2 independent recurrence groups (rows 0-15 /
// 16-31), each with its own flags + ping-pong h slots. Per step s the WG
// processes item(g=0,s) then item(g=1,s): while group 0's publish->notify
// (~8us LLC latency) is in flight, group 1's item computes -> period per
// group-chain approaches L + C/2 instead of L + C. Data path per item is
// exactly R7: store->vmcnt ack->flag; consumers poll flags, one agent acquire
// fence (L1+L2 inv), then plain cached loads. mi/mo/x register-prefetched.
__global__ __launch_bounds__(NTHR, 2) void lstm_main(
    const float* __restrict__ x, const float* __restrict__ c0,
    const float* __restrict__ Wih, const float* __restrict__ Whh,
    const float* __restrict__ bih, const float* __restrict__ bhh,
    const float* __restrict__ mi, const float* __restrict__ mo,
    float* __restrict__ out,
    _Float16* __restrict__ y0m, _Float16* __restrict__ h0b,
    _Float16* __restrict__ h1b, unsigned* __restrict__ flag0,
    unsigned* __restrict__ flag1)
{
    __shared__ _Float16 W_s[32 * 2048];         // 128 KB
    __shared__ float scr[8][16][17];            // per-wave D tiles [wave][batch16][gate16+pad]
    __shared__ float c_s[BATCH][8];             // persistent cell state (f32, global batch)
    __shared__ alignas(16) _Float16 st_h[16][8];
    __shared__ alignas(16) _Float16 st_y[16][8];
    __shared__ float st_o[16][8];

    const int bid   = blockIdx.x;
    const int layer = bid >> 7;
    const int wgl   = bid & 127;
    const int tid   = threadIdx.x;

    // ---- one-time: stage this WG's weight slice into LDS (f16, swizzled) ----
    const float* WihL = Wih + (size_t)layer * 4 * HID * HID;
    const float* WhhL = Whh + (size_t)layer * 4 * HID * HID;
    for (int idx = tid; idx < 32 * 2048; idx += NTHR) {
        int r = idx >> 11, k = idx & 2047;             // r: local gate-row (gate=r>>3, col=r&7)
        int grow = (r >> 3) * HID + wgl * 8 + (r & 7);
        float v = (k < HID) ? WihL[(size_t)grow * HID + k]
                            : WhhL[(size_t)grow * HID + (k - HID)];
        W_s[idx ^ ((r & 7) << 3)] = (_Float16)v;       // XOR-swizzle (16B granules)
    }

    // ---- cell-state init (256 threads cover all 32 batches x 8 cols) ----
    if (tid < 256) {
        int b_ = tid >> 3, c_ = tid & 7;
        c_s[b_][c_] = c0[((size_t)layer * BATCH + b_) * HID + wgl * 8 + c_];
    }

    // ---- act-thread params (tid<128): (batch-local bl, col) ----
    float bias0 = 0.f, bias1 = 0.f, bias2 = 0.f, bias3 = 0.f;
    int blA = 0, colA = 0, gcolA = 0;
    if (tid < 128) {
        blA = tid >> 3; colA = tid & 7; gcolA = wgl * 8 + colA;
        bias0 = bih[layer*4096 + gcolA]          + bhh[layer*4096 + gcolA];
        bias1 = bih[layer*4096 + HID + gcolA]    + bhh[layer*4096 + HID + gcolA];
        bias2 = bih[layer*4096 + 2*HID + gcolA]  + bhh[layer*4096 + 2*HID + gcolA];
        bias3 = bih[layer*4096 + 3*HID + gcolA]  + bhh[layer*4096 + 3*HID + gcolA];
    }
    const int ot  = tid - 256;                  // L1 out-store threads (waves 4-5): ot in [0,128)
    const int bO  = (ot >= 0 && ot < 128) ? (ot >> 3) : 0;
    const int cO  = (ot >= 0 && ot < 128) ? (ot & 7) : 0;
    __syncthreads();

    const int lane = tid & 63, wid = tid >> 6;
    // L0: waves 0-3 = h-half (kq 2,3; pollers live here, no global stores);
    //     waves 4-7 = x-half (kq 0,1; register-prefetched; wid7 publishes).
    // L1: plain kq = wid>>1 (y0m kq<2, h1 kq>=2).
    int kq;
    if (layer == 0) kq = (wid < 4) ? (2 + (wid >> 1)) : ((wid - 4) >> 1);
    else            kq = wid >> 1;
    const int half = wid & 1;                   // gate-row half: 0 -> rows 0-15 (i,f), 1 -> 16-31 (g,o)
    const int l15 = lane & 15, ko = (lane >> 4) * 8;
    const int gr  = half * 16 + l15;            // W_s row for the B fragment

    // ---- initial register prefetches (item g=0, s=0) ----
    half8 aF[16];
    float mi_pf = 0.f, mo_pf = 0.f;
    if (layer == 0 && kq < 2) {
        const float* xp = x + (size_t)l15 * HID + kq * 512 + ko;       // s=0,g=0: batch=l15
        #pragma unroll
        for (int kk = 0; kk < 16; ++kk) aF[kk] = cvt8(xp + kk * 32);
    }
    if (layer == 0 && tid < 128) mi_pf = mi[(size_t)blA * HID + gcolA];
    if (layer == 1 && ot >= 0 && ot < 128) mo_pf = mo[(size_t)bO * HID + wgl * 8 + cO];

    for (int s = 0; s < T_STEPS; ++s) {
        for (int g = 0; g < 2; ++g) {
            // ---- wait: poll this group's flags (pollers have no pending stores) ----
            if (layer == 0) {
                if (tid < 128) {
                    const unsigned* f = flag0 + (size_t)(g * 128 + tid) * 32;
                    while (lda32(f) < (unsigned)s) {}
                }
            } else {
                if (tid < 128) {
                    const unsigned* f = flag0 + (size_t)(g * 128 + tid) * 32;
                    while (lda32(f) < (unsigned)(s + 1)) {}
                } else if (tid < 256) {
                    const unsigned* f = flag1 + (size_t)(g * 128 + tid - 128) * 32;
                    while (lda32(f) < (unsigned)s) {}
                }
            }
            asm volatile("" ::: "memory");
            __syncthreads();
            if (tid == 0) __builtin_amdgcn_fence(__ATOMIC_ACQUIRE, "agent");
            __syncthreads();

            // ---- dependent A fragments: plain cached loads (post-inv) ----
            if (layer == 0) {
                if (kq >= 2) {
                    const _Float16* hp = h0b + (size_t)(s & 1) * HB
                                       + (size_t)(g * 16 + l15) * HID + (kq - 2) * 512 + ko;
                    #pragma unroll
                    for (int kk = 0; kk < 16; ++kk) aF[kk] = *(const half8*)(hp + kk * 32);
                }
            } else {
                if (kq < 2) {
                    const _Float16* yp = y0m + ((size_t)s * BATCH + g * 16 + l15) * HID
                                       + kq * 512 + ko;
                    #pragma unroll
                    for (int kk = 0; kk < 16; ++kk) aF[kk] = *(const half8*)(yp + kk * 32);
                } else {
                    const _Float16* hp = h1b + (size_t)(s & 1) * HB
                                       + (size_t)(g * 16 + l15) * HID + (kq - 2) * 512 + ko;
                    #pragma unroll
                    for (int kk = 0; kk < 16; ++kk) aF[kk] = *(const half8*)(hp + kk * 32);
                }
            }

            // ---- MFMA: D[batch16][gate16] over this wave's K quarter ----
            f32x4 acc = {0.f, 0.f, 0.f, 0.f};
            #pragma unroll
            for (int kk = 0; kk < 16; ++kk) {
                const int k = kq * 512 + kk * 32 + ko;
                const half8 bB = *(const half8*)&W_s[(gr * 2048 + k) ^ ((gr & 7) << 3)];
                acc = __builtin_amdgcn_mfma_f32_16x16x32_f16(aF[kk], bB, acc, 0, 0, 0);
            }
            #pragma unroll
            for (int j = 0; j < 4; ++j)
                scr[wid][(lane >> 4) * 4 + j][l15] = acc[j];
            __syncthreads();

            // ---- activations (tid<128): sum K-quarters; even waves = i/f, odd = g/o ----
            if (tid < 128) {
                float v0 = scr[0][blA][colA]   + scr[2][blA][colA]
                         + scr[4][blA][colA]   + scr[6][blA][colA];
                float v1 = scr[0][blA][8+colA] + scr[2][blA][8+colA]
                         + scr[4][blA][8+colA] + scr[6][blA][8+colA];
                float v2 = scr[1][blA][colA]   + scr[3][blA][colA]
                         + scr[5][blA][colA]   + scr[7][blA][colA];
                float v3 = scr[1][blA][8+colA] + scr[3][blA][8+colA]
                         + scr[5][blA][8+colA] + scr[7][blA][8+colA];
                const float ig = 1.f / (1.f + __expf(-(v0 + bias0)));
                const float fg = 1.f / (1.f + __expf(-(v1 + bias1)));
                const float gg = tanhf(v2 + bias2);
                const float og = 1.f / (1.f + __expf(-(v3 + bias3)));
                const int gb = g * 16 + blA;
                const float cc = fg * c_s[gb][colA] + ig * gg;
                const float hh = og * tanhf(cc);
                c_s[gb][colA] = cc;

                st_h[blA][colA] = (_Float16)hh;
                if (layer == 0) st_y[blA][colA] = (_Float16)(hh * mi_pf);
                else            st_o[blA][colA] = hh;

                if (s == T_STEPS - 1) {
                    const size_t base = (size_t)T_STEPS * BATCH * HID;
                    out[base + ((size_t)layer * BATCH + gb) * HID + gcolA] = hh;
                    out[base + (size_t)2 * BATCH * HID
                        + ((size_t)layer * BATCH + gb) * HID + gcolA] = cc;
                }
            }
            __syncthreads();

            // ---- publish + prefetch tails ----
            const int gn = g ^ 1;
            const int sn = s + (g == 1);
            if (layer == 0) {
                if (wid == 7) {
                    if (lane < 16) {
                        st_coh16(&h0b[(size_t)((s + 1) & 1) * HB
                                      + (size_t)(g * 16 + lane) * HID + wgl * 8],
                                 *(const half8*)st_h[lane]);
                    } else if (lane < 32) {
                        st_coh16(&y0m[((size_t)s * BATCH + g * 16 + lane - 16) * HID + wgl * 8],
                                 *(const half8*)st_y[lane - 16]);
                    }
                    asm volatile("s_waitcnt vmcnt(0)" ::: "memory");
                    if (lane == 0)
                        sta32(flag0 + (size_t)(g * 128 + wgl) * 32, (unsigned)(s + 1));
                }
                if (wid >= 4 && kq < 2 && sn < T_STEPS) {      // x prefetch for next item
                    const float* xp = x + ((size_t)sn * BATCH + gn * 16 + l15) * HID
                                    + kq * 512 + ko;
                    #pragma unroll
                    for (int kk = 0; kk < 16; ++kk) aF[kk] = cvt8(xp + kk * 32);
                }
                if (tid < 128 && sn < T_STEPS)                  // mi prefetch for next item
                    mi_pf = mi[((size_t)sn * BATCH + gn * 16 + blA) * HID + gcolA];
            } else {
                if (wid == 7) {
                    if (lane < 16) {
                        st_coh16(&h1b[(size_t)((s + 1) & 1) * HB
                                      + (size_t)(g * 16 + lane) * HID + wgl * 8],
                                 *(const half8*)st_h[lane]);
                    }
                    asm volatile("s_waitcnt vmcnt(0)" ::: "memory");
                    if (lane == 0)
                        sta32(flag1 + (size_t)(g * 128 + wgl) * 32, (unsigned)(s + 1));
                }
                if (ot >= 0 && ot < 128) {
                    out[((size_t)s * BATCH + g * 16 + bO) * HID + wgl * 8 + cO]
                        = st_o[bO][cO] * mo_pf;
                    if (sn < T_STEPS)
                        mo_pf = mo[((size_t)sn * BATCH + gn * 16 + bO) * HID + wgl * 8 + cO];
                }
            }
        }
    }
}

extern "C" void kernel_launch(void* const* d_in, const int* in_sizes, int n_in,
                              void* d_out, int out_size, void* d_ws, size_t ws_size,
                              hipStream_t stream) {
    const float* x   = (const float*)d_in[0];
    const float* h0  = (const float*)d_in[1];
    const float* c0  = (const float*)d_in[2];
    const float* Wih = (const float*)d_in[3];
    const float* Whh = (const float*)d_in[4];
    const float* bih = (const float*)d_in[5];
    const float* bhh = (const float*)d_in[6];
    const float* mi  = (const float*)d_in[7];
    const float* mo  = (const float*)d_in[8];
    float* out = (float*)d_out;

    char* w = (char*)d_ws;
    _Float16* y0m   = (_Float16*)w;                                // 13,107,200 B
    _Float16* h0b   = (_Float16*)(w + 13107200);                   //   131,072 B (2 slots)
    _Float16* h1b   = (_Float16*)(w + 13238272);                   //   131,072 B
    unsigned* flag0 = (unsigned*)(w + 13369344);                   //    32,768 B (2 groups x 128)
    unsigned* flag1 = (unsigned*)(w + 13402112);                   //    32,768 B

    hipLaunchKernelGGL(init_k, dim3(128), dim3(256), 0, stream,
                       h0, h0b, h1b, flag0, flag1);

    void* args[] = {(void*)&x, (void*)&c0, (void*)&Wih, (void*)&Whh,
                    (void*)&bih, (void*)&bhh, (void*)&mi, (void*)&mo,
                    (void*)&out, (void*)&y0m, (void*)&h0b, (void*)&h1b,
                    (void*)&flag0, (void*)&flag1};
    hipLaunchCooperativeKernel((void*)lstm_main, dim3(256), dim3(NTHR),
                               args, 0, stream);
}

// Round 14
// 2027.878 us; speedup vs baseline: 1.6492x; 1.6492x over previous
//
#include <hip/hip_runtime.h>

#define T_STEPS 200
#define BATCH   32
#define HID     1024
#define NWG     256
#define NTHR    512

typedef _Float16 half8 __attribute__((ext_vector_type(8)));
typedef float    f32x4 __attribute__((ext_vector_type(4)));

// Producer-side coherent (agent-scope, cache-bypassing) 16B store from two
// relaxed 8B atomics: write-through to LLC, never dirty in L2.
__device__ __forceinline__ void st_coh16(_Float16* p, half8 v) {
    union { half8 h; unsigned long long u[2]; } r; r.h = v;
    unsigned long long* q = (unsigned long long*)p;
    __hip_atomic_store(q,     r.u[0], __ATOMIC_RELAXED, __HIP_MEMORY_SCOPE_AGENT);
    __hip_atomic_store(q + 1, r.u[1], __ATOMIC_RELAXED, __HIP_MEMORY_SCOPE_AGENT);
}

__device__ __forceinline__ half8 cvt8(const float* p) {
    f32x4 lo = *(const f32x4*)p;
    f32x4 hi = *(const f32x4*)(p + 4);
    half8 a;
    a[0] = (_Float16)lo[0]; a[1] = (_Float16)lo[1];
    a[2] = (_Float16)lo[2]; a[3] = (_Float16)lo[3];
    a[4] = (_Float16)hi[0]; a[5] = (_Float16)hi[1];
    a[6] = (_Float16)hi[2]; a[7] = (_Float16)hi[3];
    return a;
}

__global__ void init_k(const float* __restrict__ h0,
                       _Float16* __restrict__ h0b, _Float16* __restrict__ h1b,
                       unsigned* __restrict__ flag0, unsigned* __restrict__ flag1) {
    int i = blockIdx.x * blockDim.x + threadIdx.x;
    if (i < BATCH * HID) {
        h0b[i] = (_Float16)h0[i];                 // layer 0 initial h -> slot 0
        h1b[i] = (_Float16)h0[BATCH * HID + i];   // layer 1 initial h -> slot 0
    }
    if (blockIdx.x == 0) {
        if (threadIdx.x < 128)      flag0[threadIdx.x * 32] = 0;
        else if (threadIdx.x < 256) flag1[(threadIdx.x - 128) * 32] = 0;
    }
}

// Self-timed dataflow LSTM, NO global barrier. Consumers read the exchanged
// h/y0m with PLAIN CACHED loads; coherence via one agent-scope acquire fence
// (buffer_inv: L1+L2 invalidate) per WG per tick, executed after the
// flag-wait. Producers store write-through to LLC (agent-scope atomics) +
// vmcnt ack + flag, so all exchange data is at the LLC before any consumer's
// post-inv L2 fill.
__global__ __launch_bounds__(NTHR, 2) void lstm_main(
    const float* __restrict__ x, const float* __restrict__ c0,
    const float* __restrict__ Wih, const float* __restrict__ Whh,
    const float* __restrict__ bih, const float* __restrict__ bhh,
    const float* __restrict__ mi, const float* __restrict__ mo,
    float* __restrict__ out,
    _Float16* __restrict__ y0m, _Float16* __restrict__ h0b,
    _Float16* __restrict__ h1b, unsigned* __restrict__ flag0,
    unsigned* __restrict__ flag1)
{
    __shared__ _Float16 W_s[32 * 2048];     // 128 KB
    __shared__ float scr[8][2][16][17];     // per-(kq,mm) partial gate tiles
    __shared__ float c_s[BATCH][8];         // persistent cell state (f32)
    __shared__ alignas(16) _Float16 st_h[BATCH][8];  // staged h for wave-7 stores
    __shared__ alignas(16) _Float16 st_y[BATCH][8];  // staged y0*mask (layer 0)
    __shared__ float st_o[BATCH][8];        // staged h for out-stores (layer 1)

    const int bid   = blockIdx.x;
    const int layer = bid >> 7;
    const int wgl   = bid & 127;
    const int tid   = threadIdx.x;

    // ---- one-time: stage this WG's weight slice into LDS (f16, swizzled) ----
    const float* WihL = Wih + (size_t)layer * 4 * HID * HID;
    const float* WhhL = Whh + (size_t)layer * 4 * HID * HID;
    for (int idx = tid; idx < 32 * 2048; idx += NTHR) {
        int r = idx >> 11, k = idx & 2047;             // r: local gate-row
        int grow = (r >> 3) * HID + wgl * 8 + (r & 7); // global row in [4H]
        float v = (k < HID) ? WihL[(size_t)grow * HID + k]
                            : WhhL[(size_t)grow * HID + (k - HID)];
        W_s[idx ^ ((r & 7) << 3)] = (_Float16)v;       // XOR-swizzle (16B granules)
    }

    float bias0 = 0.f, bias1 = 0.f, bias2 = 0.f, bias3 = 0.f;
    int b_ = 0, col_ = 0, gcol = 0;
    if (tid < 256) {
        b_ = tid >> 3; col_ = tid & 7; gcol = wgl * 8 + col_;
        bias0 = bih[layer * 4096 + gcol]           + bhh[layer * 4096 + gcol];
        bias1 = bih[layer * 4096 + HID + gcol]     + bhh[layer * 4096 + HID + gcol];
        bias2 = bih[layer * 4096 + 2 * HID + gcol] + bhh[layer * 4096 + 2 * HID + gcol];
        bias3 = bih[layer * 4096 + 3 * HID + gcol] + bhh[layer * 4096 + 3 * HID + gcol];
        c_s[b_][col_] = c0[((size_t)layer * BATCH + b_) * HID + gcol];
    }
    // out-store / mask threads (waves 4-7): own (b2, c2)
    const int ot = tid - 256;
    const int b2 = (ot >= 0) ? (ot >> 3) : 0, c2 = (ot >= 0) ? (ot & 7) : 0;
    const int gcol2 = wgl * 8 + c2;
    __syncthreads();

    const int lane = tid & 63, wid = tid >> 6;
    // layer 0: waves 0-3 own the h-half (kq 2,3); waves 4-7 own the x-half
    // (kq 0,1, register-prefetched). layer 1: plain kq = wid>>1.
    int kq;
    if (layer == 0) kq = (wid < 4) ? (2 + (wid >> 1)) : ((wid - 4) >> 1);
    else            kq = wid >> 1;
    const int mm   = wid & 1;
    const int srow = kq * 2 + mm;          // scr slot (logical, not wid)
    const int row = lane & 15, bb = mm * 16 + row, ko = (lane >> 4) * 8;

    // ---- prefetched pure-t state ----
    half8 aF[16];
    float mi_reg = 0.f, mo_reg = 0.f;
    if (layer == 0 && kq < 2) {
        const float* xp = x + (size_t)bb * HID + kq * 512 + ko;   // s = 0
        #pragma unroll
        for (int kk = 0; kk < 16; ++kk) aF[kk] = cvt8(xp + kk * 32);
    }
    if (layer == 1 && ot >= 0) mo_reg = mo[(size_t)b2 * HID + gcol2];  // s = 0

    for (int s = 0; s < T_STEPS; ++s) {
        // ---- dataflow wait (lane-private spins; no pending stores here) ----
        if (layer == 0) {
            if (tid < 128) {
                const unsigned* f = flag0 + tid * 32;
                const unsigned tgt = (unsigned)s;
                while (__hip_atomic_load(f, __ATOMIC_RELAXED,
                                         __HIP_MEMORY_SCOPE_AGENT) < tgt) {}
            }
        } else {
            if (tid < 128) {
                const unsigned* f = flag0 + tid * 32;
                const unsigned tgt = (unsigned)(s + 1);
                while (__hip_atomic_load(f, __ATOMIC_RELAXED,
                                         __HIP_MEMORY_SCOPE_AGENT) < tgt) {}
            } else if (tid < 256) {
                const unsigned* f = flag1 + (tid - 128) * 32;
                const unsigned tgt = (unsigned)s;
                while (__hip_atomic_load(f, __ATOMIC_RELAXED,
                                         __HIP_MEMORY_SCOPE_AGENT) < tgt) {}
            }
        }
        asm volatile("" ::: "memory");
        __syncthreads();
        // ---- acquire: invalidate L1+L2 so plain loads see the LLC data ----
        if (tid == 0) __builtin_amdgcn_fence(__ATOMIC_ACQUIRE, "agent");
        __syncthreads();

        // ---- mask load for this step (hidden under MFMA phase) ----
        if (layer == 0 && tid < 256)
            mi_reg = mi[((size_t)s * BATCH + b_) * HID + gcol];

        // ---- dependent A fragments: PLAIN CACHED loads (L2-shared fills) ----
        if (layer == 0) {
            if (kq >= 2) {
                const _Float16* hp = h0b + (s & 1) * (BATCH * HID)
                                   + bb * HID + (kq - 2) * 512 + ko;
                #pragma unroll
                for (int kk = 0; kk < 16; ++kk)
                    aF[kk] = *(const half8*)(hp + kk * 32);
            }
        } else {
            if (kq < 2) {
                const _Float16* yp = y0m + ((size_t)s * BATCH + bb) * HID + kq * 512 + ko;
                #pragma unroll
                for (int kk = 0; kk < 16; ++kk)
                    aF[kk] = *(const half8*)(yp + kk * 32);
            } else {
                const _Float16* hp = h1b + (s & 1) * (BATCH * HID)
                                   + bb * HID + (kq - 2) * 512 + ko;
                #pragma unroll
                for (int kk = 0; kk < 16; ++kk)
                    aF[kk] = *(const half8*)(hp + kk * 32);
            }
        }

        // ---- MFMA: D[batch 16][gaterow 16] x2 subtiles over K=512 ----
        f32x4 acc0 = {0.f, 0.f, 0.f, 0.f}, acc1 = {0.f, 0.f, 0.f, 0.f};
        #pragma unroll
        for (int kk = 0; kk < 16; ++kk) {
            const int k  = kq * 512 + kk * 32 + ko;
            const int r1 = 16 + row;
            const half8 bB0 = *(const half8*)&W_s[(row * 2048 + k) ^ ((row & 7) << 3)];
            const half8 bB1 = *(const half8*)&W_s[(r1 * 2048 + k) ^ ((r1 & 7) << 3)];
            acc0 = __builtin_amdgcn_mfma_f32_16x16x32_f16(aF[kk], bB0, acc0, 0, 0, 0);
            acc1 = __builtin_amdgcn_mfma_f32_16x16x32_f16(aF[kk], bB1, acc1, 0, 0, 0);
        }
        #pragma unroll
        for (int j = 0; j < 4; ++j) {
            scr[srow][0][(lane >> 4) * 4 + j][row] = acc0[j];
            scr[srow][1][(lane >> 4) * 4 + j][row] = acc1[j];
        }
        __syncthreads();

        // ---- activations: thread owns (batch b_, hidden col gcol) ----
        if (tid < 256) {
            const int m2 = b_ >> 4, rD = b_ & 15;
            float v0 = 0.f, v1 = 0.f, v2 = 0.f, v3 = 0.f;
            #pragma unroll
            for (int q = 0; q < 4; ++q) {
                v0 += scr[q * 2 + m2][0][rD][col_];       // gate i
                v1 += scr[q * 2 + m2][0][rD][8 + col_];   // gate f
                v2 += scr[q * 2 + m2][1][rD][col_];       // gate g
                v3 += scr[q * 2 + m2][1][rD][8 + col_];   // gate o
            }
            const float ig = 1.f / (1.f + __expf(-(v0 + bias0)));
            const float fg = 1.f / (1.f + __expf(-(v1 + bias1)));
            const float gg = tanhf(v2 + bias2);
            const float og = 1.f / (1.f + __expf(-(v3 + bias3)));
            const float cc = fg * c_s[b_][col_] + ig * gg;
            const float hh = og * tanhf(cc);
            c_s[b_][col_] = cc;

            st_h[b_][col_] = (_Float16)hh;
            if (layer == 0) st_y[b_][col_] = (_Float16)(hh * mi_reg);
            else            st_o[b_][col_] = hh;

            if (s == T_STEPS - 1) {
                const size_t base = (size_t)T_STEPS * BATCH * HID;
                // agent-scope stores: write-through, never dirty in L2 (inv-safe)
                __hip_atomic_store(&out[base + ((size_t)layer * BATCH + b_) * HID + gcol],
                                   hh, __ATOMIC_RELAXED, __HIP_MEMORY_SCOPE_AGENT);
                __hip_atomic_store(&out[base + (size_t)2 * BATCH * HID
                                        + ((size_t)layer * BATCH + b_) * HID + gcol],
                                   cc, __ATOMIC_RELAXED, __HIP_MEMORY_SCOPE_AGENT);
            }
        }
        __syncthreads();

        // ---- producer tails ----
        if (layer == 0) {
            if (wid >= 4) {
                if (tid >= 448 && tid < 480) {
                    // wave 7 lower half: coherent stores -> ack -> flag
                    const int sl = tid - 448;
                    st_coh16(&h0b[((s + 1) & 1) * (BATCH * HID) + sl * HID + wgl * 8],
                             *(const half8*)st_h[sl]);
                    st_coh16(&y0m[((size_t)s * BATCH + sl) * HID + wgl * 8],
                             *(const half8*)st_y[sl]);
                    asm volatile("s_waitcnt vmcnt(0)" ::: "memory");
                    if (tid == 448)
                        __hip_atomic_store(flag0 + wgl * 32, (unsigned)(s + 1),
                                           __ATOMIC_RELAXED, __HIP_MEMORY_SCOPE_AGENT);
                }
                // x prefetch for s+1 (after the flag: ack never waits on HBM)
                if (kq < 2 && s + 1 < T_STEPS) {
                    const float* xp = x + ((size_t)(s + 1) * BATCH + bb) * HID + kq * 512 + ko;
                    #pragma unroll
                    for (int kk = 0; kk < 16; ++kk) aF[kk] = cvt8(xp + kk * 32);
                }
            }
        } else {
            if (ot >= 0) {
                // agent-scope out store: write-through (inv-safe)
                __hip_atomic_store(&out[((size_t)s * BATCH + b2) * HID + gcol2],
                                   st_o[b2][c2] * mo_reg,
                                   __ATOMIC_RELAXED, __HIP_MEMORY_SCOPE_AGENT);
                if (tid >= 448 && tid < 480) {
                    const int sl = tid - 448;
                    st_coh16(&h1b[((s + 1) & 1) * (BATCH * HID) + sl * HID + wgl * 8],
                             *(const half8*)st_h[sl]);
                    asm volatile("s_waitcnt vmcnt(0)" ::: "memory");
                    if (tid == 448)
                        __hip_atomic_store(flag1 + wgl * 32, (unsigned)(s + 1),
                                           __ATOMIC_RELAXED, __HIP_MEMORY_SCOPE_AGENT);
                }
                if (s + 1 < T_STEPS)
                    mo_reg = mo[((size_t)(s + 1) * BATCH + b2) * HID + gcol2];
            }
        }
    }
}

extern "C" void kernel_launch(void* const* d_in, const int* in_sizes, int n_in,
                              void* d_out, int out_size, void* d_ws, size_t ws_size,
                              hipStream_t stream) {
    const float* x   = (const float*)d_in[0];
    const float* h0  = (const float*)d_in[1];
    const float* c0  = (const float*)d_in[2];
    const float* Wih = (const float*)d_in[3];
    const float* Whh = (const float*)d_in[4];
    const float* bih = (const float*)d_in[5];
    const float* bhh = (const float*)d_in[6];
    const float* mi  = (const float*)d_in[7];
    const float* mo  = (const float*)d_in[8];
    float* out = (float*)d_out;

    char* w = (char*)d_ws;
    _Float16* y0m   = (_Float16*)w;                                // 13,107,200 B
    _Float16* h0b   = (_Float16*)(w + 13107200);                   //   131,072 B (2 slots)
    _Float16* h1b   = (_Float16*)(w + 13107200 + 131072);          //   131,072 B
    unsigned* flag0 = (unsigned*)(w + 13107200 + 262144);          //    16,384 B
    unsigned* flag1 = (unsigned*)(w + 13107200 + 262144 + 16384);  //    16,384 B

    hipLaunchKernelGGL(init_k, dim3(128), dim3(256), 0, stream,
                       h0, h0b, h1b, flag0, flag1);

    void* args[] = {(void*)&x, (void*)&c0, (void*)&Wih, (void*)&Whh,
                    (void*)&bih, (void*)&bhh, (void*)&mi, (void*)&mo,
                    (void*)&out, (void*)&y0m, (void*)&h0b, (void*)&h1b,
                    (void*)&flag0, (void*)&flag1};
    hipLaunchCooperativeKernel((void*)lstm_main, dim3(NWG), dim3(NTHR),
                               args, 0, stream);
}